// Round 4
// baseline (251.489 us; speedup 1.0000x reference)
//
#include <hip/hip_runtime.h>
#include <math.h>

// Problem constants: H=1024, B=32, S=4096, all f32.
constexpr int H = 1024;
constexpr int B = 32;
constexpr int S = 4096;
constexpr int NBLK  = 1024;       // 4 blocks/CU x 256 CUs — exactly co-resident capacity
constexpr int TILES = 32;         // s-tiles per b
constexpr int TROWS = S / TILES;  // 128 rows per tile

// ws layout: [0,256) barrier state (zeroed each launch) | [1024,+128K) v | then stats (B*TILES*2 f32)

// ---------------------------------------------------------------------------
// Kernel 1: v[b,h] = sum_g hidden[b,g]*W[g,h].  float4 W loads, 8-way g-split,
// MODEST unroll (2 float4 live per step) — anti-spill version of R2's k1.
// ---------------------------------------------------------------------------
__global__ __launch_bounds__(256) void compute_v_kernel(
    const float* __restrict__ hidden, const float* __restrict__ W,
    float* __restrict__ v)
{
    const int b  = blockIdx.x >> 3;
    const int hc = blockIdx.x & 7;
    const int hq = threadIdx.x & 31;
    const int gg = threadIdx.x >> 5;
    const int hquad = hc * 32 + hq;
    const float* __restrict__ hb = hidden + b * H;
    const float4* __restrict__ W4 = (const float4*)W;

    float4 aE = {0,0,0,0}, aO = {0,0,0,0};
    const int g0 = gg * 128;
    #pragma unroll 4
    for (int g = g0; g < g0 + 128; g += 2) {
        float  h0 = hb[g], h1 = hb[g + 1];
        float4 w0 = W4[(size_t)g * 256 + hquad];
        float4 w1 = W4[((size_t)g + 1) * 256 + hquad];
        aE.x = fmaf(h0, w0.x, aE.x); aE.y = fmaf(h0, w0.y, aE.y);
        aE.z = fmaf(h0, w0.z, aE.z); aE.w = fmaf(h0, w0.w, aE.w);
        aO.x = fmaf(h1, w1.x, aO.x); aO.y = fmaf(h1, w1.y, aO.y);
        aO.z = fmaf(h1, w1.z, aO.z); aO.w = fmaf(h1, w1.w, aO.w);
    }
    float4 acc = {aE.x + aO.x, aE.y + aO.y, aE.z + aO.z, aE.w + aO.w};

    __shared__ float4 part[8][32];
    part[gg][hq] = acc;
    __syncthreads();
    if (gg == 0) {
        float4 s = part[0][hq];
        #pragma unroll
        for (int k = 1; k < 8; ++k) {
            float4 p = part[k][hq];
            s.x += p.x; s.y += p.y; s.z += p.z; s.w += p.w;
        }
        ((float4*)(v + b * H))[hquad] = s;
    }
}

// ---------------------------------------------------------------------------
// Sense-reversing grid barrier, device scope. Thread 0's acq_rel RMW flushes/
// invalidates the XCD L2 (cache ops act on the shared cache, so the block's
// plain stores — already drained to L2 by __syncthreads — are covered).
// ---------------------------------------------------------------------------
__device__ __forceinline__ void grid_barrier(int* count, int* gen) {
    __syncthreads();
    if (threadIdx.x == 0) {
        int g = __hip_atomic_load(gen, __ATOMIC_ACQUIRE, __HIP_MEMORY_SCOPE_AGENT);
        int a = __hip_atomic_fetch_add(count, 1, __ATOMIC_ACQ_REL, __HIP_MEMORY_SCOPE_AGENT);
        if (a == NBLK - 1) {
            __hip_atomic_store(count, 0, __ATOMIC_RELAXED, __HIP_MEMORY_SCOPE_AGENT);
            __hip_atomic_fetch_add(gen, 1, __ATOMIC_ACQ_REL, __HIP_MEMORY_SCOPE_AGENT);
        } else {
            while (__hip_atomic_load(gen, __ATOMIC_ACQUIRE, __HIP_MEMORY_SCOPE_AGENT) == g)
                __builtin_amdgcn_s_sleep(2);
        }
    }
    __syncthreads();
}

// ---------------------------------------------------------------------------
// Fused energies + softmax. Block = (b, s-tile of 128 rows). Energies live in
// LDS across the grid barrier (no HBM round-trip); only per-tile (max, expsum)
// stats cross blocks (8 KiB). Phase 2 combines stats and writes the output.
// ---------------------------------------------------------------------------
__global__ __launch_bounds__(256, 4) void fused_kernel(
    const float* __restrict__ enc, const float* __restrict__ v,
    float* __restrict__ stats, int* __restrict__ bar,
    float* __restrict__ out)
{
    const int b  = blockIdx.x >> 5;
    const int t  = blockIdx.x & 31;
    const int s0 = t * TROWS;
    const int wave = threadIdx.x >> 6;
    const int lane = threadIdx.x & 63;

    __shared__ float4 vs[H / 4];      // 4 KiB
    __shared__ float  en[TROWS];      // 512 B — persists across grid_barrier
    __shared__ float  red[8];
    __shared__ float  fin[2];

    vs[threadIdx.x] = ((const float4*)(v + b * H))[threadIdx.x];
    __syncthreads();
    const float4 w0 = vs[lane],       w1 = vs[64 + lane],
                 w2 = vs[128 + lane], w3 = vs[192 + lane];

    // ---- Phase 1: energies for this tile (one row per wave-iteration) ----
    for (int si = wave; si < TROWS; si += 4) {
        const int s = s0 + si;
        const float4* __restrict__ row =
            (const float4*)(enc + ((size_t)s * B + b) * H);
        float4 e0 = row[lane],       e1 = row[64 + lane],
               e2 = row[128 + lane], e3 = row[192 + lane];
        float p0 = e0.x * w0.x, p1 = e1.x * w1.x;
        p0 = fmaf(e0.y, w0.y, p0); p1 = fmaf(e1.y, w1.y, p1);
        p0 = fmaf(e0.z, w0.z, p0); p1 = fmaf(e1.z, w1.z, p1);
        p0 = fmaf(e0.w, w0.w, p0); p1 = fmaf(e1.w, w1.w, p1);
        p0 = fmaf(e2.x, w2.x, p0); p1 = fmaf(e3.x, w3.x, p1);
        p0 = fmaf(e2.y, w2.y, p0); p1 = fmaf(e3.y, w3.y, p1);
        p0 = fmaf(e2.z, w2.z, p0); p1 = fmaf(e3.z, w3.z, p1);
        p0 = fmaf(e2.w, w2.w, p0); p1 = fmaf(e3.w, w3.w, p1);
        float acc = p0 + p1;
        #pragma unroll
        for (int off = 32; off > 0; off >>= 1)
            acc += __shfl_xor(acc, off, 64);
        if (lane == 0) en[si] = acc;
    }
    __syncthreads();

    // ---- Tile stats: m_t = max(en), s_t = sum(exp(en - m_t)) ----
    float e = (threadIdx.x < TROWS) ? en[threadIdx.x] : -INFINITY;
    float m = e;
    #pragma unroll
    for (int off = 32; off > 0; off >>= 1)
        m = fmaxf(m, __shfl_xor(m, off, 64));
    if (lane == 0) red[wave] = m;
    __syncthreads();
    m = fmaxf(fmaxf(red[0], red[1]), fmaxf(red[2], red[3]));
    float p = (threadIdx.x < TROWS) ? __expf(e - m) : 0.f;
    float sum = p;
    #pragma unroll
    for (int off = 32; off > 0; off >>= 1)
        sum += __shfl_xor(sum, off, 64);
    if (lane == 0) red[4 + wave] = sum;
    __syncthreads();
    if (threadIdx.x == 0) {
        stats[(b * TILES + t) * 2 + 0] = m;
        stats[(b * TILES + t) * 2 + 1] = red[4] + red[5] + red[6] + red[7];
    }

    grid_barrier(bar + 0, bar + 1);

    // ---- Phase 2: combine stats for this b, normalize, write out ----
    if (wave == 0) {
        float mt = (lane < TILES) ? stats[(b * TILES + lane) * 2 + 0] : -INFINITY;
        float st = (lane < TILES) ? stats[(b * TILES + lane) * 2 + 1] : 0.f;
        float mb = mt;
        #pragma unroll
        for (int off = 32; off > 0; off >>= 1)
            mb = fmaxf(mb, __shfl_xor(mb, off, 64));
        float sc = st * __expf(mt - mb);      // lane>=TILES: 0 * 0 = 0
        #pragma unroll
        for (int off = 32; off > 0; off >>= 1)
            sc += __shfl_xor(sc, off, 64);
        if (lane == 0) { fin[0] = mb; fin[1] = 1.0f / sc; }
    }
    __syncthreads();
    if (threadIdx.x < TROWS)
        out[(size_t)b * S + s0 + threadIdx.x] =
            __expf(en[threadIdx.x] - fin[0]) * fin[1];
}

extern "C" void kernel_launch(void* const* d_in, const int* in_sizes, int n_in,
                              void* d_out, int out_size, void* d_ws, size_t ws_size,
                              hipStream_t stream) {
    const float* hidden = (const float*)d_in[0];   // [1, B, H]
    const float* enc    = (const float*)d_in[1];   // [S, B, H]
    const float* W      = (const float*)d_in[2];   // [H, H]
    // d_in[3] = attn_b: per-b constant in energies -> cancels under softmax.
    float* out = (float*)d_out;                    // [B, 1, S]

    int*   bar   = (int*)d_ws;                                   // 256 B
    float* v     = (float*)((char*)d_ws + 1024);                 // 128 KiB
    float* stats = (float*)((char*)d_ws + 1024 + (size_t)B * H * 4); // 8 KiB

    hipMemsetAsync(d_ws, 0, 256, stream);          // zero barrier state each call
    compute_v_kernel<<<dim3(B * 8), dim3(256), 0, stream>>>(hidden, W, v);
    fused_kernel<<<dim3(NBLK), dim3(256), 0, stream>>>(enc, v, stats, bar, out);
}